// Round 7
// baseline (146.692 us; speedup 1.0000x reference)
//
#include <hip/hip_runtime.h>
#include <math.h>

#define HW 4096      // 64*64 feature locations
#define CC 256       // feature channels
#define C2 64        // value channels
#define E50f 1.928749848e-22f   // expf(-50)

typedef unsigned short USH;
typedef __attribute__((ext_vector_type(8))) _Float16 f16x8;
typedef __attribute__((ext_vector_type(8))) short bf8;
typedef __attribute__((ext_vector_type(4))) float f32x4;

__device__ __forceinline__ USH f2bf(float x) {
    unsigned u = __float_as_uint(x);
    u += 0x7fff + ((u >> 16) & 1);   // round-to-nearest-even
    return (USH)(u >> 16);
}
__device__ __forceinline__ USH f2h(float x) {
    _Float16 h = (_Float16)x;        // v_cvt_f16_f32, RTNE
    return *(USH*)&h;
}
__device__ __forceinline__ float h2f(USH u) {
    _Float16 h = *(_Float16*)&u;
    return (float)h;
}

// async global->LDS DMA, 16B per lane; LDS base must be wave-uniform
__device__ __forceinline__ void gl2lds16(const USH* g, USH* l) {
    __builtin_amdgcn_global_load_lds(
        (const __attribute__((address_space(1))) void*)g,
        (__attribute__((address_space(3))) void*)l, 16, 0, 0);
}

// ---------------------------------------------------------------------------
// D1: single-pass prep.
//  blocks [0,128): which=x&1, pblk=x>>1: read 64p x 256c of fa/fb ONCE ->
//    raw fp16 transposed chunked [kc][p][32], Sxx[p] (from fp16 values),
//    colsum partials [which][pblk][c].
//  blocks [128,1152): bilinear 256->64 of unalign_fb + mask_b + vtT build
//    (chunked [qc][256m][32] bf16) + bg partials. (unchanged from R6)
__global__ __launch_bounds__(256) void k_prep(
    const float* __restrict__ fa, const float* __restrict__ fb,
    USH* __restrict__ faT, USH* __restrict__ fbT,
    float* __restrict__ Sxx, float* __restrict__ colsum,
    const float* __restrict__ ufb_src, const int* __restrict__ fb_parse,
    USH* __restrict__ vtT, float* __restrict__ bgp) {
    __shared__ float tile[64][68];
    __shared__ float cs[64][4];
    __shared__ float sx[64][4];
    __shared__ float4 sred[256];
    int t = threadIdx.x;
    if (blockIdx.x < 128) {
        int which = blockIdx.x & 1;
        int pblk = blockIdx.x >> 1;
        int p0 = pblk * 64;
        const float* src = which ? fb : fa;
        USH* dst = which ? fbT : faT;
        int c_r = t >> 2, seg = t & 3;
        float sxx_acc = 0.f;
        for (int ci = 0; ci < 4; ++ci) {
            int c0 = ci * 64;
            float lsum = 0.f;
            {
                const float* s = &src[(size_t)(c0 + c_r) * HW + p0 + seg * 16];
#pragma unroll
                for (int k = 0; k < 4; ++k) {
                    float4 v = *(const float4*)&s[k * 4];
                    *(float4*)&tile[c_r][seg * 16 + k * 4] = v;
                    lsum += v.x + v.y + v.z + v.w;
                }
            }
            cs[c_r][seg] = lsum;
            __syncthreads();
            if (t < 64)
                colsum[(which * 64 + pblk) * 256 + c0 + t] =
                    cs[t][0] + cs[t][1] + cs[t][2] + cs[t][3];
            {
                int p_r = c_r;          // t>>2
                int cl = seg * 16;
                union { USH us[8]; uint4 v; } h0, h1;
#pragma unroll
                for (int j = 0; j < 8; ++j) {
                    USH h = f2h(tile[cl + j][p_r]);
                    float xv = h2f(h);
                    sxx_acc += xv * xv;
                    h0.us[j] = h;
                }
#pragma unroll
                for (int j = 0; j < 8; ++j) {
                    USH h = f2h(tile[cl + 8 + j][p_r]);
                    float xv = h2f(h);
                    sxx_acc += xv * xv;
                    h1.us[j] = h;
                }
                int kc = ci * 2 + (seg >> 1);
                size_t base = (size_t)kc * 131072 + (size_t)(p0 + p_r) * 32 + (seg & 1) * 16;
                *(uint4*)&dst[base] = h0.v;
                *(uint4*)&dst[base + 8] = h1.v;
            }
            __syncthreads();
        }
        sx[c_r][seg] = sxx_acc;
        __syncthreads();
        if (t < 64)
            Sxx[which * HW + p0 + t] = sx[t][0] + sx[t][1] + sx[t][2] + sx[t][3];
        return;
    }
    int bid = blockIdx.x - 128;
    int pblk = bid & 15, c = bid >> 4;
    int p = pblk * 256 + t;
    int j = p >> 6, i = p & 63;
    int off = (4 * j) * 256 + 4 * i;   // nearest: src = 4*dst
    float m0 = (fb_parse[1 * 65536 + off] != 0) ? 1.f : 0.f;
    float m1 = (fb_parse[2 * 65536 + off] != 0) ? 1.f : 0.f;
    float m2 = (fb_parse[3 * 65536 + off] != 0) ? 1.f : 0.f;
    float ry = j * (255.0f / 63.0f);
    int y0 = (int)ry; y0 = min(y0, 255); int y1 = min(y0 + 1, 255);
    float wy = ry - (float)y0;
    float rx = i * (255.0f / 63.0f);
    int x0 = (int)rx; x0 = min(x0, 255); int x1 = min(x0 + 1, 255);
    float wx = rx - (float)x0;
    const float* sc = ufb_src + c * 65536;
    float r0 = sc[y0 * 256 + x0] * (1.f - wx) + sc[y0 * 256 + x1] * wx;
    float r1 = sc[y1 * 256 + x0] * (1.f - wx) + sc[y1 * 256 + x1] * wx;
    float v = r0 * (1.f - wy) + r1 * wy;
    size_t cbase = (size_t)(p >> 5) * 8192 + (p & 31);
    vtT[cbase + (0 * 65 + c) * 32] = f2bf(v * m0);
    vtT[cbase + (1 * 65 + c) * 32] = f2bf(v * m1);
    vtT[cbase + (2 * 65 + c) * 32] = f2bf(v * m2);
    if (c == 0) {
        vtT[cbase + 64 * 32]  = f2bf(m0);
        vtT[cbase + 129 * 32] = f2bf(m1);
        vtT[cbase + 194 * 32] = f2bf(m2);
        for (int m = 195; m < 256; ++m) vtT[cbase + m * 32] = 0;
    }
    sred[t] = make_float4(v, v * m0, v * m1, v * m2);
    __syncthreads();
    for (int st = 128; st > 0; st >>= 1) {
        if (t < st) {
            float4 o = sred[t + st];
            sred[t].x += o.x; sred[t].y += o.y; sred[t].z += o.z; sred[t].w += o.w;
        }
        __syncthreads();
    }
    if (t == 0) {
        float4 r = sred[0];
        bgp[pblk * 320 + 256 + c]     = r.x;   // tot[c]
        bgp[pblk * 320 + 0 * 65 + c]  = r.y;   // rowsum value rows
        bgp[pblk * 320 + 1 * 65 + c]  = r.z;
        bgp[pblk * 320 + 2 * 65 + c]  = r.w;
    }
    __syncthreads();
    if (c == 0) {   // mask-row sums (block-uniform branch)
        sred[t] = make_float4(m0, m1, m2, 0.f);
        __syncthreads();
        for (int st = 128; st > 0; st >>= 1) {
            if (t < st) {
                float4 o = sred[t + st];
                sred[t].x += o.x; sred[t].y += o.y; sred[t].z += o.z;
            }
            __syncthreads();
        }
        if (t == 0) {
            float4 r = sred[0];
            bgp[pblk * 320 + 64]  = r.x;
            bgp[pblk * 320 + 129] = r.y;
            bgp[pblk * 320 + 194] = r.z;
        }
    }
}

// D2: mu from colsum partials; K = mu_a.mu_b, Sa = |mu_a|^2, Sb = |mu_b|^2
// stats: [0..255] mu_a, [256..511] mu_b, [512]=K, [513]=Sa, [514]=Sb
__global__ void k_stats(const float* __restrict__ colsum, float* __restrict__ stats) {
    __shared__ float4 sred[256];
    int t = threadIdx.x;
    float s0 = 0.f, s1 = 0.f;
    for (int pb = 0; pb < 64; ++pb) {
        s0 += colsum[(0 * 64 + pb) * 256 + t];
        s1 += colsum[(1 * 64 + pb) * 256 + t];
    }
    float mu0 = s0 * (1.0f / HW), mu1 = s1 * (1.0f / HW);
    stats[t] = mu0;
    stats[256 + t] = mu1;
    sred[t] = make_float4(mu0 * mu1, mu0 * mu0, mu1 * mu1, 0.f);
    __syncthreads();
    for (int st = 128; st > 0; st >>= 1) {
        if (t < st) {
            float4 o = sred[t + st];
            sred[t].x += o.x; sred[t].y += o.y; sred[t].z += o.z;
        }
        __syncthreads();
    }
    if (t == 0) {
        stats[512] = sred[0].x;   // K
        stats[513] = sred[0].y;   // Sa
        stats[514] = sred[0].z;   // Sb
    }
}

// D3: per-location corrections from the fp16 operands.
// dra: [0..4095] da (fa side), [4096..8191] db (fb side),
//      [8192..12287] ra, [12288..16383] rb
__global__ void k_corr(const USH* __restrict__ faT, const USH* __restrict__ fbT,
                       const float* __restrict__ Sxx, const float* __restrict__ stats,
                       float* __restrict__ dra) {
    __shared__ float smu[512];
    __shared__ float scc[4];
    int t = threadIdx.x;
    int which = blockIdx.y;
    smu[t] = stats[t];
    smu[256 + t] = stats[256 + t];
    if (t < 3) scc[t] = stats[512 + t];
    __syncthreads();
    int p = blockIdx.x * 256 + t;
    const USH* xT = which ? fbT : faT;
    const float* mu_self = &smu[which * 256];
    const float* mu_oth  = &smu[(1 - which) * 256];
    float ca = 0.f, da = 0.f;
    for (int kc = 0; kc < 8; ++kc) {
        union { uint4 v; USH us[8]; } u[4];
        size_t base = (size_t)kc * 131072 + (size_t)p * 32;
#pragma unroll
        for (int g = 0; g < 4; ++g) u[g].v = *(const uint4*)&xT[base + g * 8];
#pragma unroll
        for (int g = 0; g < 4; ++g)
#pragma unroll
            for (int jj = 0; jj < 8; ++jj) {
                float xv = h2f(u[g].us[jj]);
                int c = kc * 32 + g * 8 + jj;
                ca += xv * mu_self[c];
                da += xv * mu_oth[c];
            }
    }
    float Sself = scc[1 + which];   // Sa or Sb
    float ra = rsqrtf(Sxx[which * HW + p] - 2.f * ca + Sself);
    dra[which * HW + p] = da;
    dra[2 * HW + which * HW + p] = ra;
}

// D4: fused attention. S = (G - da[p] - db[q] + K)*ra[p]*rb[q] with G from raw
// fp16 MFMA; E = exp(100S-50) bf16 in LDS; PV = vtT.E^T with vtT A-fragments
// loaded DIRECTLY from global (16B-contiguous in chunked layout) - no sV LDS.
// Block: p-tile 64 (x), z-chunk 512 q (y). 4 q-tiles of 128. 3 blocks/CU.
__global__ __launch_bounds__(256, 3) void k_attn(
    const USH* __restrict__ faT, const USH* __restrict__ fbT,
    const USH* __restrict__ vtT, const float* __restrict__ dra,
    const float* __restrict__ stats, float* __restrict__ part) {
    __shared__ USH sA[2][2048];     // faT stage [64p][32k] fp16
    __shared__ USH sB[2][4096];     // fbT stage [128q][32k] fp16
    __shared__ USH sE[64 * 136];    // E tile [64p][128q + pad] bf16
    int t = threadIdx.x;
    int p0 = blockIdx.x * 64;
    int z = blockIdx.y;
    int w = t >> 6, lane = t & 63, lr = lane & 15, quad = lane >> 4;
    f32x4 accp[4][4] = {};          // PV acc: m=64w+16i+quad*4+r, p=p0+16j+lr

    const USH* gA = faT + (size_t)p0 * 32;
    float Kc = stats[512];
    float da4[4], ra4[4];
#pragma unroll
    for (int jj = 0; jj < 4; ++jj) {
        da4[jj] = dra[p0 + 16 * jj + lr];
        ra4[jj] = dra[2 * HW + p0 + 16 * jj + lr];
    }

#define DMA_AB(buf, kc, q0)                                                          \
    do {                                                                             \
        gl2lds16(gA + (size_t)(kc) * 131072 + w * 512 + lane * 8, &sA[buf][w * 512]);\
        _Pragma("unroll")                                                            \
        for (int cc = 0; cc < 2; ++cc)                                               \
            gl2lds16(fbT + (size_t)(kc) * 131072 + (size_t)(q0) * 32 +               \
                         (2 * w + cc) * 512 + lane * 8,                              \
                     &sB[buf][(2 * w + cc) * 512]);                                  \
    } while (0)

    DMA_AB(0, 0, z * 512);
    __syncthreads();
    for (int qt = 0; qt < 4; ++qt) {
        int q0 = z * 512 + qt * 128;
        f32x4 accs[2][4] = {};      // S acc: q=32w+16i+quad*4+r, p=16j+lr
        for (int kc = 0; kc < 8; ++kc) {
            int cur = kc & 1;
            if (kc < 7)      DMA_AB(cur ^ 1, kc + 1, q0);
            else if (qt < 3) DMA_AB(0, 0, q0 + 128);
            f16x8 a[2], b[4];
#pragma unroll
            for (int i = 0; i < 2; ++i)
                a[i] = *(const f16x8*)&sB[cur][(32 * w + 16 * i + lr) * 32 + quad * 8];
#pragma unroll
            for (int jj = 0; jj < 4; ++jj)
                b[jj] = *(const f16x8*)&sA[cur][(16 * jj + lr) * 32 + quad * 8];
#pragma unroll
            for (int i = 0; i < 2; ++i)
#pragma unroll
                for (int jj = 0; jj < 4; ++jj)
                    accs[i][jj] = __builtin_amdgcn_mfma_f32_16x16x32_f16(a[i], b[jj], accs[i][jj], 0, 0, 0);
            __syncthreads();
        }
        // corrections + exp -> bf16 -> transposed E tile in LDS: E[p][q]
#pragma unroll
        for (int i = 0; i < 2; ++i) {
            int qb = q0 + 32 * w + 16 * i + 4 * quad;
            float4 db4 = *(const float4*)&dra[HW + qb];
            float4 rb4 = *(const float4*)&dra[3 * HW + qb];
#pragma unroll
            for (int jj = 0; jj < 4; ++jj) {
                float rr = ra4[jj];
                float dd = da4[jj] - Kc;
                float s0 = (accs[i][jj][0] - dd - db4.x) * (rr * rb4.x);
                float s1 = (accs[i][jj][1] - dd - db4.y) * (rr * rb4.y);
                float s2 = (accs[i][jj][2] - dd - db4.z) * (rr * rb4.z);
                float s3 = (accs[i][jj][3] - dd - db4.w) * (rr * rb4.w);
                unsigned u0 = ((unsigned)f2bf(__expf(fmaf(100.f, s1, -50.f))) << 16)
                            | (unsigned)f2bf(__expf(fmaf(100.f, s0, -50.f)));
                unsigned u1 = ((unsigned)f2bf(__expf(fmaf(100.f, s3, -50.f))) << 16)
                            | (unsigned)f2bf(__expf(fmaf(100.f, s2, -50.f)));
                int addr = (16 * jj + lr) * 136 + 32 * w + 16 * i + 4 * quad;
                uint2 u; u.x = u0; u.y = u1;
                *(uint2*)&sE[addr] = u;
            }
        }
        __syncthreads();
        // PV: vtT A-fragments straight from global (L2-hot), no barriers
#pragma unroll
        for (int kc = 0; kc < 4; ++kc) {
            size_t vbase = (size_t)(z * 16 + qt * 4 + kc) * 8192 + (size_t)quad * 8;
            bf8 av[4], be[4];
#pragma unroll
            for (int i = 0; i < 4; ++i)
                av[i] = *(const bf8*)&vtT[vbase + (64 * w + 16 * i + lr) * 32];
#pragma unroll
            for (int jj = 0; jj < 4; ++jj)
                be[jj] = *(const bf8*)&sE[(16 * jj + lr) * 136 + kc * 32 + quad * 8];
#pragma unroll
            for (int i = 0; i < 4; ++i)
#pragma unroll
                for (int jj = 0; jj < 4; ++jj)
                    accp[i][jj] = __builtin_amdgcn_mfma_f32_16x16x32_bf16(av[i], be[jj], accp[i][jj], 0, 0, 0);
        }
        __syncthreads();
    }
#undef DMA_AB
    float* op = part + (size_t)z * 1048576;
#pragma unroll
    for (int i = 0; i < 4; ++i) {
        int m = 64 * w + 16 * i + quad * 4;
#pragma unroll
        for (int jj = 0; jj < 4; ++jj) {
            int pc = p0 + 16 * jj + lr;
#pragma unroll
            for (int r = 0; r < 4; ++r)
                op[(size_t)(m + r) * HW + pc] = accp[i][jj][r];
        }
    }
}

// D5: aligned[c2][p]: 8 z-slices summed inline; mask_a/norm_a from fa_parse;
//     bg terms from the 16 per-pblock partial slots
__global__ void k_combine8(const float* __restrict__ part, const float* __restrict__ bgp,
                           const int* __restrict__ fa_parse, float* __restrict__ aligned) {
    __shared__ float sums[8];
    int t = threadIdx.x;
    int c2 = blockIdx.y;
    if (t < 7) {
        int idx = (t < 3) ? (t * 65 + 64) : ((t < 6) ? (t - 3) * 65 + c2 : 256 + c2);
        float s = 0.f;
#pragma unroll
        for (int pb = 0; pb < 16; ++pb) s += bgp[pb * 320 + idx];
        sums[t] = s;
    }
    __syncthreads();
    int p = blockIdx.x * 256 + t;
    int jj = p >> 6, ii = p & 63;
    int off = (4 * jj) * 256 + 4 * ii;
    float num = 0.f, s = 0.f;
    for (int k = 0; k < 3; ++k) {
        float ma = (fa_parse[(k + 1) * 65536 + off] != 0) ? 1.f : 0.f;
        s += ma;
        float den = E50f * (4096.0f - sums[k]);
        float nu  = E50f * (sums[6] - sums[3 + k]);
        size_t rd = (size_t)(k * 65 + 64) * HW + p;
        size_t rn = (size_t)(k * 65 + c2) * HW + p;
#pragma unroll
        for (int z = 0; z < 8; ++z) {
            den += part[(size_t)z * 1048576 + rd];
            nu  += part[(size_t)z * 1048576 + rn];
        }
        num += ma * (nu / den);
    }
    aligned[c2 * HW + p] = num / fmaxf(s, 1.f);
}

// D6: bilinear align_corners 64->256, 4 outputs per thread
__global__ void k_bilin_up(const float* __restrict__ aligned, float* __restrict__ out) {
    int idx = (blockIdx.x * 256 + threadIdx.x) * 4;
    int c2 = blockIdx.y;
    int y = idx >> 8;
    float ry = y * (63.0f / 255.0f);
    int y0 = (int)ry; y0 = min(y0, 63); int y1 = min(y0 + 1, 63);
    float wy = ry - (float)y0;
    const float* a = aligned + c2 * HW;
    float4 o;
    float* op = &o.x;
#pragma unroll
    for (int u = 0; u < 4; ++u) {
        int x = (idx & 255) + u;
        float rx = x * (63.0f / 255.0f);
        int x0 = (int)rx; x0 = min(x0, 63); int x1 = min(x0 + 1, 63);
        float wx = rx - (float)x0;
        float r0 = a[y0 * 64 + x0] * (1.f - wx) + a[y0 * 64 + x1] * wx;
        float r1 = a[y1 * 64 + x0] * (1.f - wx) + a[y1 * 64 + x1] * wx;
        op[u] = r0 * (1.f - wy) + r1 * wy;
    }
    *(float4*)&out[c2 * 65536 + idx] = o;
}

extern "C" void kernel_launch(void* const* d_in, const int* in_sizes, int n_in,
                              void* d_out, int out_size, void* d_ws, size_t ws_size,
                              hipStream_t stream) {
    const float* unalign_fb = (const float*)d_in[0];   // (1,64,256,256)
    const float* fa         = (const float*)d_in[1];   // (1,256,64,64)
    const int*   fa_parse   = (const int*)d_in[2];     // (1,4,256,256)
    const float* fb         = (const float*)d_in[3];   // (1,256,64,64)
    const int*   fb_parse   = (const int*)d_in[4];     // (1,4,256,256)
    float* out = (float*)d_out;                         // (1,64,256,256)

    float* w = (float*)d_ws;
    float* stats   = w;                    // 1024 (515 used)
    float* colsum  = w + 1024;             // 2*64*256 = 32768
    float* Sxx     = w + 33792;            // 8192
    float* dra     = w + 41984;            // 16384
    float* bgp     = w + 58368;            // 16*320 = 5120
    float* part    = w + 63488;            // 8*1048576
    float* aligned = w + 8452096;          // 262144
    USH* faT = (USH*)(w + 8714240);        // [kc=8][4096p][32] fp16 (raw)
    USH* fbT = (USH*)(w + 9238528);        // [kc=8][4096q][32] fp16 (raw)
    USH* vtT = (USH*)(w + 9762816);        // [qc=128][256m][32] bf16
    // total ~10.29M floats = ~41.1 MB

    k_prep<<<dim3(1152), dim3(256), 0, stream>>>(fa, fb, faT, fbT, Sxx, colsum,
                                                 unalign_fb, fb_parse, vtT, bgp);
    k_stats<<<dim3(1), dim3(256), 0, stream>>>(colsum, stats);
    k_corr<<<dim3(16, 2), dim3(256), 0, stream>>>(faT, fbT, Sxx, stats, dra);
    k_attn<<<dim3(64, 8), dim3(256), 0, stream>>>(faT, fbT, vtT, dra, stats, part);
    k_combine8<<<dim3(16, 64), dim3(256), 0, stream>>>(part, bgp, fa_parse, aligned);
    k_bilin_up<<<dim3(64, 64), dim3(256), 0, stream>>>(aligned, out);
}